// Round 1
// baseline (308.077 us; speedup 1.0000x reference)
//
#include <hip/hip_runtime.h>

// QuantizationLayer: x in [0,1)  ->  n = round_half_even(x * 2^B - 0.5) in [0, 2^B)
// -> emit B bits MSB-first as float32 (0.0 / 1.0).
//
// B == 4 fast path: each input element produces exactly one float4 output,
// perfectly aligned (out offset = i*16 bytes). Grid-stride loop, cap blocks.

__global__ __launch_bounds__(256) void quant_bits4_kernel(
    const float* __restrict__ x, float* __restrict__ out, int n_elems) {
    int idx = blockIdx.x * blockDim.x + threadIdx.x;
    int stride = gridDim.x * blockDim.x;
    float4* __restrict__ out4 = reinterpret_cast<float4*>(out);
    for (int i = idx; i < n_elems; i += stride) {
        float v = x[i];
        // x*16 is exact (pow2 scale), so mul+sub == fma; v_rndne_f32 == np.round
        float q = rintf(v * 16.0f - 0.5f);
        int n = (int)q;             // in [0, 15]; rintf(-0.5) = -0.0 -> 0
        float4 o;
        o.x = (float)((n >> 3) & 1);
        o.y = (float)((n >> 2) & 1);
        o.z = (float)((n >> 1) & 1);
        o.w = (float)(n & 1);
        out4[i] = o;
    }
}

// Generic fallback for any B (1..8)
__global__ __launch_bounds__(256) void quant_bits_generic_kernel(
    const float* __restrict__ x, float* __restrict__ out, int n_elems, int B) {
    int idx = blockIdx.x * blockDim.x + threadIdx.x;
    int stride = gridDim.x * blockDim.x;
    float step = (float)(1 << B);
    for (int i = idx; i < n_elems; i += stride) {
        float v = x[i];
        int n = (int)rintf(v * step - 0.5f);
        for (int j = 0; j < B; ++j) {
            out[(long long)i * B + j] = (float)((n >> (B - 1 - j)) & 1);
        }
    }
}

extern "C" void kernel_launch(void* const* d_in, const int* in_sizes, int n_in,
                              void* d_out, int out_size, void* d_ws, size_t ws_size,
                              hipStream_t stream) {
    const float* x = (const float*)d_in[0];
    float* out = (float*)d_out;
    int n = in_sizes[0];
    int B = out_size / n;  // bits per element, known on host

    const int threads = 256;
    int blocks = (n + threads - 1) / threads;
    if (blocks > 2048) blocks = 2048;

    if (B == 4) {
        quant_bits4_kernel<<<blocks, threads, 0, stream>>>(x, out, n);
    } else {
        quant_bits_generic_kernel<<<blocks, threads, 0, stream>>>(x, out, n, B);
    }
}